// Round 1
// baseline (645.338 us; speedup 1.0000x reference)
//
#include <hip/hip_runtime.h>
#include <stdint.h>

namespace {

constexpr int kBH = 128;
constexpr int kS  = 1024;
constexpr int kD  = 64;
constexpr int kQB = 32;
constexpr int kStride = kS + 4;                  // f32 LDS stride: 2-way banks (free), 16B aligned
constexpr float kScale = 0.04419417382415922f;   // 1/sqrt(512)  (temper = sqrt(d_model))
constexpr float kNegInf = -3.0e38f;

typedef __attribute__((ext_vector_type(8))) short short8;  // 8 bf16 (4 VGPRs)
typedef __attribute__((ext_vector_type(4))) float f32x4;
typedef __attribute__((ext_vector_type(4))) int   i32x4;

__device__ inline short f2bf(float f) {          // f32 -> bf16 bits, RNE
    union { float f; uint32_t u; } x; x.f = f;
    uint32_t r = x.u + 0x7fffu + ((x.u >> 16) & 1u);
    return (short)(r >> 16);
}

__global__ __launch_bounds__(512)
void sdpa_kernel(const float* __restrict__ Q, const float* __restrict__ K,
                 const float* __restrict__ V, const int* __restrict__ M,
                 float* __restrict__ Og, float* __restrict__ Ag) {
    __shared__ float s_lds[kQB * kStride];       // 131,584 B raw scores -> exp(p)
    __shared__ float inv_lds[kQB];

    // XCD-aware swizzle: 4096 WGs, 8 XCDs -> 512 consecutive logical WGs per XCD,
    // so each bh's 32 q-tiles share one XCD's L2 (K+V = 512 KB resident).
    const int logical = (blockIdx.x & 7) * 512 + (blockIdx.x >> 3);
    const int bh = logical >> 5;
    const int q0 = (logical & 31) * kQB;

    const int tid  = threadIdx.x;
    const int wave = tid >> 6;
    const int lane = tid & 63;
    const int l16  = lane & 15;
    const int lg   = lane >> 4;

    const float* qb = Q + (size_t)bh * kS * kD;
    const float* kb = K + (size_t)bh * kS * kD;
    const float* vb = V + (size_t)bh * kS * kD;

    // ---- Q fragments (2 m-tiles x 2 k-steps), A[row=l16][k=lg*8+j] ----
    short8 afr[2][2];
    #pragma unroll
    for (int m = 0; m < 2; ++m)
    #pragma unroll
    for (int ks = 0; ks < 2; ++ks) {
        const float* p = qb + (size_t)(q0 + m * 16 + l16) * kD + ks * 32 + lg * 8;
        short8 t;
        #pragma unroll
        for (int j = 0; j < 8; ++j) t[j] = f2bf(p[j]);
        afr[m][ks] = t;
    }

    // ---- Phase 1: raw QK^T scores -> LDS; wave owns 128-col slice ----
    const int n0 = wave * 128;
    for (int nt = 0; nt < 8; ++nt) {
        const int nb = n0 + nt * 16;
        short8 bfr[2];
        #pragma unroll
        for (int ks = 0; ks < 2; ++ks) {
            const float* p = kb + (size_t)(nb + l16) * kD + ks * 32 + lg * 8;
            short8 t;
            #pragma unroll
            for (int j = 0; j < 8; ++j) t[j] = f2bf(p[j]);
            bfr[ks] = t;
        }
        #pragma unroll
        for (int m = 0; m < 2; ++m) {
            f32x4 acc = {0.f, 0.f, 0.f, 0.f};
            acc = __builtin_amdgcn_mfma_f32_16x16x32_bf16(afr[m][0], bfr[0], acc, 0, 0, 0);
            acc = __builtin_amdgcn_mfma_f32_16x16x32_bf16(afr[m][1], bfr[1], acc, 0, 0, 0);
            const int rbase = m * 16 + lg * 4;   // C/D: col=lane&15, row=(lane>>4)*4+r
            #pragma unroll
            for (int r = 0; r < 4; ++r)
                s_lds[(rbase + r) * kStride + nb + l16] = acc[r];
        }
    }
    __syncthreads();

    // ---- Phase 2: mask+scale -> rowmax -> exp -> rowsum -> attn write ----
    {
        const int row = tid >> 4;                // 32 rows x 16 threads
        const int c0  = (tid & 15) * 4;
        const int* mrow = M + ((size_t)bh * kS + q0 + row) * kS;
        float* srow = s_lds + row * kStride;

        float mx = kNegInf;
        #pragma unroll
        for (int i = 0; i < 16; ++i) {
            const int c = c0 + i * 64;           // int4/float4, 256B coalesced per 16 threads
            i32x4 mk = *(const i32x4*)(mrow + c);
            f32x4 s  = *(const f32x4*)(srow + c);
            f32x4 e;
            e.x = mk.x ? kNegInf : s.x * kScale;
            e.y = mk.y ? kNegInf : s.y * kScale;
            e.z = mk.z ? kNegInf : s.z * kScale;
            e.w = mk.w ? kNegInf : s.w * kScale;
            *(f32x4*)(srow + c) = e;
            mx = fmaxf(mx, fmaxf(fmaxf(e.x, e.y), fmaxf(e.z, e.w)));
        }
        #pragma unroll
        for (int o = 8; o; o >>= 1) mx = fmaxf(mx, __shfl_xor(mx, o));

        float sum = 0.f;
        #pragma unroll
        for (int i = 0; i < 16; ++i) {
            const int c = c0 + i * 64;
            f32x4 s = *(const f32x4*)(srow + c);
            f32x4 p;
            p.x = __expf(s.x - mx);
            p.y = __expf(s.y - mx);
            p.z = __expf(s.z - mx);
            p.w = __expf(s.w - mx);
            *(f32x4*)(srow + c) = p;             // keep UNNORMALIZED p in LDS
            sum += (p.x + p.y) + (p.z + p.w);
        }
        #pragma unroll
        for (int o = 8; o; o >>= 1) sum += __shfl_xor(sum, o);
        const float inv = 1.0f / sum;
        if ((tid & 15) == 0) inv_lds[row] = inv;

        float* arow = Ag + ((size_t)bh * kS + q0 + row) * kS;
        #pragma unroll
        for (int i = 0; i < 16; ++i) {
            const int c = c0 + i * 64;
            f32x4 p = *(const f32x4*)(srow + c);
            f32x4 a = p * inv;
            *(f32x4*)(arow + c) = a;             // coalesced float4 attn store
        }
    }
    __syncthreads();

    // ---- Phase 3: O = (P*inv) @ V; wave -> one 16x16 output tile, full K=1024 ----
    {
        const int m  = wave >> 2;                // 0..1
        const int d0 = (wave & 3) * 16;          // 0..48
        const float invr = inv_lds[m * 16 + l16];
        const float* pa0 = s_lds + (size_t)(m * 16 + l16) * kStride + lg * 8;
        f32x4 acc = {0.f, 0.f, 0.f, 0.f};
        for (int ks = 0; ks < 32; ++ks) {
            short8 a;                            // A[row=l16][k=ks*32+lg*8+j]
            const float* pa = pa0 + ks * 32;
            #pragma unroll
            for (int j = 0; j < 8; ++j) a[j] = f2bf(pa[j] * invr);
            short8 b;                            // B[k][n=d0+l16] = V[k][d]
            const float* pv = vb + (size_t)(ks * 32 + lg * 8) * kD + d0 + l16;
            #pragma unroll
            for (int j = 0; j < 8; ++j) b[j] = f2bf(pv[(size_t)j * kD]);
            acc = __builtin_amdgcn_mfma_f32_16x16x32_bf16(a, b, acc, 0, 0, 0);
        }
        float* orow = Og + ((size_t)bh * kS + q0 + m * 16 + lg * 4) * kD + d0 + l16;
        #pragma unroll
        for (int r = 0; r < 4; ++r) orow[(size_t)r * kD] = acc[r];
    }
}

} // namespace

extern "C" void kernel_launch(void* const* d_in, const int* in_sizes, int n_in,
                              void* d_out, int out_size, void* d_ws, size_t ws_size,
                              hipStream_t stream) {
    const float* q = (const float*)d_in[0];
    const float* k = (const float*)d_in[1];
    const float* v = (const float*)d_in[2];
    const int*   m = (const int*)d_in[3];
    float* og = (float*)d_out;
    float* ag = og + (size_t)kBH * kS * kD;      // outputs concatenated: O then attn
    sdpa_kernel<<<dim3(kBH * (kS / kQB)), dim3(512), 0, stream>>>(q, k, v, m, og, ag);
}